// Round 1
// baseline (341.032 us; speedup 1.0000x reference)
//
#include <hip/hip_runtime.h>
#include <hip/hip_bf16.h>

typedef _Float16 f16;
typedef _Float16 f16x8 __attribute__((ext_vector_type(8)));
typedef _Float16 f16x4 __attribute__((ext_vector_type(4)));
typedef float f32x4 __attribute__((ext_vector_type(4)));

constexpr int B_ = 4, HDIM = 256, WDIM = 256, C_ = 192, NH_ = 6, HD = 32;
constexpr int NWIN = 4096;               // 4 * 32 * 32
constexpr float SCALE = 0.17677669529663687f;  // 32^-0.5

// workspace layout (bytes), all 256B-aligned
constexpr size_t OFF_WQ  = 0;                         // 576*192 f16 = 221184
constexpr size_t OFF_WP  = 221184;                    // 192*192 f16 = 73728
constexpr size_t OFF_Q   = 294912;                    // 4096*6*64*32 f16 = 100663296
constexpr size_t OFF_K   = OFF_Q  + 100663296ull;
constexpr size_t OFF_VT  = OFF_K  + 100663296ull;
constexpr size_t OFF_ATT = OFF_VT + 100663296ull;     // 4096*64*192 f16

__global__ __launch_bounds__(256) void prep_weights(const float* __restrict__ qkv_w,
                                                    const float* __restrict__ proj_w,
                                                    f16* __restrict__ wq, f16* __restrict__ wp) {
    int i = blockIdx.x * 256 + threadIdx.x;
    if (i < 576 * 192) wq[i] = (f16)qkv_w[i];
    if (i < 192 * 192) wp[i] = (f16)proj_w[i];
}

// ---------------- QKV projection: one window (64 tokens) per block, 4 waves ----------------
__global__ __launch_bounds__(256) void qkv_kernel(const float* __restrict__ x,
                                                  const f16* __restrict__ wq,
                                                  f16* __restrict__ qh, f16* __restrict__ kh,
                                                  f16* __restrict__ vth) {
    __shared__ f16 wlds[192 * 200];   // 192 rows of W-chunk, +8 f16 pad (row stride 400B)
    const int tid = threadIdx.x;
    const int wv = tid >> 6;
    const int lane = tid & 63;
    const int l15 = lane & 15, lg = lane >> 4;
    const int win = blockIdx.x;
    const int b = win >> 10, wy = (win >> 5) & 31, wx = win & 31;

    // A fragments: row = token (wv*16 + l15), k = 8*lg .. within each 32-k step
    const int t = wv * 16 + l15;
    const int gy = wy * 8 + (t >> 3), gx = wx * 8 + (t & 7);
    const float* xrow = x + ((size_t)((b * HDIM + gy) * WDIM + gx)) * C_;
    f16x8 afrag[6];
#pragma unroll
    for (int ks = 0; ks < 6; ++ks) {
        const float4* p = (const float4*)(xrow + ks * 32 + lg * 8);
        float4 u0 = p[0], u1 = p[1];
        f16x8 a;
        a[0] = (f16)u0.x; a[1] = (f16)u0.y; a[2] = (f16)u0.z; a[3] = (f16)u0.w;
        a[4] = (f16)u1.x; a[5] = (f16)u1.y; a[6] = (f16)u1.z; a[7] = (f16)u1.w;
        afrag[ks] = a;
    }

    for (int c = 0; c < 3; ++c) {   // c: 0=q, 1=k, 2=v  (576 cols = 3 chunks of 192)
        if (c) __syncthreads();
        // stage 192x192 f16 chunk of W into LDS (18 x 16B per thread)
        const uint4* src = (const uint4*)(wq + c * 192 * 192);
#pragma unroll
        for (int it = 0; it < 18; ++it) {
            int i = tid + it * 256;               // 16B unit index, [0,4608)
            int row = i / 24, col8 = i % 24;
            *((uint4*)(wlds + row * 200 + col8 * 8)) = src[i];
        }
        __syncthreads();

#pragma unroll
        for (int nt = 0; nt < 12; ++nt) {
            f32x4 acc = {0.f, 0.f, 0.f, 0.f};
#pragma unroll
            for (int ks = 0; ks < 6; ++ks) {
                f16x8 bfrag = *((const f16x8*)(wlds + (nt * 16 + l15) * 200 + ks * 32 + lg * 8));
                acc = __builtin_amdgcn_mfma_f32_16x16x32_f16(afrag[ks], bfrag, acc, 0, 0, 0);
            }
            const int head = nt >> 1;
            const int d = (nt & 1) * 16 + l15;
            const int tb = wv * 16 + lg * 4;
            if (c == 0) {
                f16* dst = qh + ((size_t)(win * NH_ + head) * 64) * HD;
#pragma unroll
                for (int i2 = 0; i2 < 4; ++i2) dst[(size_t)(tb + i2) * HD + d] = (f16)acc[i2];
            } else if (c == 1) {
                f16* dst = kh + ((size_t)(win * NH_ + head) * 64) * HD;
#pragma unroll
                for (int i2 = 0; i2 < 4; ++i2) dst[(size_t)(tb + i2) * HD + d] = (f16)acc[i2];
            } else {
                f16x4 vv;
#pragma unroll
                for (int i2 = 0; i2 < 4; ++i2) vv[i2] = (f16)acc[i2];
                f16* dst = vth + ((size_t)(win * NH_ + head) * HD + d) * 64 + tb;
                *((f16x4*)dst) = vv;   // 4 consecutive tokens, 8B store
            }
        }
    }
}

// ---------------- attention: one (window, head) per 64-thread block ----------------
__global__ __launch_bounds__(64) void attn_kernel(const f16* __restrict__ qh,
                                                  const f16* __restrict__ kh,
                                                  const f16* __restrict__ vth,
                                                  const float* __restrict__ rpb,
                                                  f16* __restrict__ att) {
    __shared__ f16 p_lds[64 * 72];   // P matrix, padded stride 72 f16 (144B)
    const int lane = threadIdx.x;
    const int l15 = lane & 15, lg = lane >> 4;
    const int wh = blockIdx.x;       // win*6 + head
    const int win = wh / 6;
    const int head = wh - win * 6;

    const f16* qbase = qh + (size_t)wh * 64 * HD;
    const f16* kbase = kh + (size_t)wh * 64 * HD;
    const f16* vbase = vth + (size_t)wh * HD * 64;

    f16x8 qf[4], kf[4];
#pragma unroll
    for (int t4 = 0; t4 < 4; ++t4) {
        qf[t4] = *((const f16x8*)(qbase + (t4 * 16 + l15) * HD + lg * 8));
        kf[t4] = *((const f16x8*)(kbase + (t4 * 16 + l15) * HD + lg * 8));
    }

    f32x4 s[4][4];
#pragma unroll
    for (int qt = 0; qt < 4; ++qt)
#pragma unroll
        for (int kt = 0; kt < 4; ++kt) {
            f32x4 z = {0.f, 0.f, 0.f, 0.f};
            s[qt][kt] = __builtin_amdgcn_mfma_f32_16x16x32_f16(qf[qt], kf[kt], z, 0, 0, 0);
        }

    // scale + relative-position bias
#pragma unroll
    for (int qt = 0; qt < 4; ++qt)
#pragma unroll
        for (int kt = 0; kt < 4; ++kt)
#pragma unroll
            for (int i = 0; i < 4; ++i) {
                int q = qt * 16 + lg * 4 + i;
                int kk = kt * 16 + l15;
                int dy = (q >> 3) - (kk >> 3) + 7;
                int dx = (q & 7) - (kk & 7) + 7;
                s[qt][kt][i] = s[qt][kt][i] * SCALE + rpb[(dy * 15 + dx) * NH_ + head];
            }

    // fp32 softmax per row (row q lives in the 16 lanes sharing lg, reg i)
#pragma unroll
    for (int qt = 0; qt < 4; ++qt) {
#pragma unroll
        for (int i = 0; i < 4; ++i) {
            float m = fmaxf(fmaxf(s[qt][0][i], s[qt][1][i]), fmaxf(s[qt][2][i], s[qt][3][i]));
            m = fmaxf(m, __shfl_xor(m, 1));
            m = fmaxf(m, __shfl_xor(m, 2));
            m = fmaxf(m, __shfl_xor(m, 4));
            m = fmaxf(m, __shfl_xor(m, 8));
            float e0 = __expf(s[qt][0][i] - m);
            float e1 = __expf(s[qt][1][i] - m);
            float e2 = __expf(s[qt][2][i] - m);
            float e3 = __expf(s[qt][3][i] - m);
            float sum = e0 + e1 + e2 + e3;
            sum += __shfl_xor(sum, 1);
            sum += __shfl_xor(sum, 2);
            sum += __shfl_xor(sum, 4);
            sum += __shfl_xor(sum, 8);
            float r = 1.0f / sum;
            int q = qt * 16 + lg * 4 + i;
            p_lds[q * 72 +  0 + l15] = (f16)(e0 * r);
            p_lds[q * 72 + 16 + l15] = (f16)(e1 * r);
            p_lds[q * 72 + 32 + l15] = (f16)(e2 * r);
            p_lds[q * 72 + 48 + l15] = (f16)(e3 * r);
        }
    }
    __syncthreads();

    // PV: out(64x32) = P(64x64) @ V(64x32), V read via vt[d][t] (contiguous B-frags)
    f16x8 vf[2][2];
#pragma unroll
    for (int dt = 0; dt < 2; ++dt)
#pragma unroll
        for (int ks = 0; ks < 2; ++ks)
            vf[dt][ks] = *((const f16x8*)(vbase + (dt * 16 + l15) * 64 + ks * 32 + lg * 8));

#pragma unroll
    for (int qt = 0; qt < 4; ++qt) {
        f16x8 pa[2];
#pragma unroll
        for (int ks = 0; ks < 2; ++ks)
            pa[ks] = *((const f16x8*)(p_lds + (qt * 16 + l15) * 72 + ks * 32 + lg * 8));
#pragma unroll
        for (int dt = 0; dt < 2; ++dt) {
            f32x4 acc = {0.f, 0.f, 0.f, 0.f};
#pragma unroll
            for (int ks = 0; ks < 2; ++ks)
                acc = __builtin_amdgcn_mfma_f32_16x16x32_f16(pa[ks], vf[dt][ks], acc, 0, 0, 0);
#pragma unroll
            for (int i = 0; i < 4; ++i) {
                int q = qt * 16 + lg * 4 + i;
                att[(size_t)(win * 64 + q) * C_ + head * 32 + dt * 16 + l15] = (f16)acc[i];
            }
        }
    }
}

// ---------------- output projection + un-windowing ----------------
__global__ __launch_bounds__(256) void proj_kernel(const f16* __restrict__ att,
                                                   const f16* __restrict__ wp,
                                                   const float* __restrict__ pb,
                                                   float* __restrict__ out) {
    __shared__ f16 wlds[192 * 200];
    const int tid = threadIdx.x;
    const int wv = tid >> 6;
    const int lane = tid & 63;
    const int l15 = lane & 15, lg = lane >> 4;
    const int win = blockIdx.x;
    const int b = win >> 10, wy = (win >> 5) & 31, wx = win & 31;

    // A fragments from att (f16, direct 16B loads)
    const f16* arow = att + (size_t)(win * 64 + wv * 16 + l15) * C_;
    f16x8 afrag[6];
#pragma unroll
    for (int ks = 0; ks < 6; ++ks)
        afrag[ks] = *((const f16x8*)(arow + ks * 32 + lg * 8));

    const uint4* src = (const uint4*)wp;
#pragma unroll
    for (int it = 0; it < 18; ++it) {
        int i = tid + it * 256;
        int row = i / 24, col8 = i % 24;
        *((uint4*)(wlds + row * 200 + col8 * 8)) = src[i];
    }
    __syncthreads();

#pragma unroll
    for (int nt = 0; nt < 12; ++nt) {
        f32x4 acc = {0.f, 0.f, 0.f, 0.f};
#pragma unroll
        for (int ks = 0; ks < 6; ++ks) {
            f16x8 bfrag = *((const f16x8*)(wlds + (nt * 16 + l15) * 200 + ks * 32 + lg * 8));
            acc = __builtin_amdgcn_mfma_f32_16x16x32_f16(afrag[ks], bfrag, acc, 0, 0, 0);
        }
        const int col = nt * 16 + l15;
        const float bias = pb[col];
        const int tb = wv * 16 + lg * 4;
#pragma unroll
        for (int i2 = 0; i2 < 4; ++i2) {
            int tt = tb + i2;
            int gy = wy * 8 + (tt >> 3), gx = wx * 8 + (tt & 7);
            out[((size_t)(b * HDIM + gy) * WDIM + gx) * C_ + col] = acc[i2] + bias;
        }
    }
}

extern "C" void kernel_launch(void* const* d_in, const int* in_sizes, int n_in,
                              void* d_out, int out_size, void* d_ws, size_t ws_size,
                              hipStream_t stream) {
    const float* x      = (const float*)d_in[0];
    const float* qkv_w  = (const float*)d_in[1];
    const float* proj_w = (const float*)d_in[2];
    const float* proj_b = (const float*)d_in[3];
    const float* rpb    = (const float*)d_in[4];
    float* out = (float*)d_out;
    char* ws = (char*)d_ws;
    f16* wq  = (f16*)(ws + OFF_WQ);
    f16* wp  = (f16*)(ws + OFF_WP);
    f16* qh  = (f16*)(ws + OFF_Q);
    f16* kh  = (f16*)(ws + OFF_K);
    f16* vth = (f16*)(ws + OFF_VT);
    f16* att = (f16*)(ws + OFF_ATT);

    prep_weights<<<432, 256, 0, stream>>>(qkv_w, proj_w, wq, wp);
    qkv_kernel<<<NWIN, 256, 0, stream>>>(x, wq, qh, kh, vth);
    attn_kernel<<<NWIN * NH_, 64, 0, stream>>>(qh, kh, vth, rpb, att);
    proj_kernel<<<NWIN, 256, 0, stream>>>(att, wp, proj_b, out);
}